// Round 7
// baseline (80.858 us; speedup 1.0000x reference)
//
#include <hip/hip_runtime.h>

#define N_CAMP 50
#define DAYS   365
#define ROW    366          // DAYS+1
#define BASIS  1e-10f
#define BATCH  4096
#define NTHR   384

// R6 winning structure: one block per batch element, thread d computes day d
// via 50 scalar dword loads (wave reads 256 B contiguous per campaign),
// single dispatch, __expf/__frcp_rn, nontemporal stores.
// R7 change: nontemporal LOADS on the 300 MB once-touched adstock stream.
__global__ __launch_bounds__(NTHR)
void transition_prob_kernel(const float* __restrict__ adstock,
                            const float* __restrict__ mu,
                            const float* __restrict__ beta,
                            const float* __restrict__ init_prob,
                            const float* __restrict__ click_prob,
                            float* __restrict__ out)
{
    __shared__ float sb0[N_CAMP];
    __shared__ float sb1[N_CAMP];
    __shared__ float sb2[N_CAMP];
    __shared__ float smu[3];

    const int tid = threadIdx.x;
    const int b   = blockIdx.x;

    if (tid < 3 * N_CAMP) {
        const int c = tid / 3;
        const int k = tid % 3;
        const float v = beta[tid];
        if (k == 0) sb0[c] = v;
        else if (k == 1) sb1[c] = v;
        else sb2[c] = v;
    }
    if (tid < 3) smu[tid] = mu[tid];
    __syncthreads();

    // Fold the two scalar sigmoids in (thread 383 never computes a day).
    if (b == 0 && tid == NTHR - 1) {
        const size_t base = (size_t)BATCH * DAYS * 9;
        __builtin_nontemporal_store(1.0f / (1.0f + __expf(-init_prob[0])), &out[base + 0]);
        __builtin_nontemporal_store(1.0f / (1.0f + __expf(-click_prob[0])), &out[base + 1]);
    }

    const int d = tid;
    if (d < DAYS) {
        const float* arow = adstock + (size_t)b * (N_CAMP * ROW) + (d + 1);

        float o1 = 0.f, o2 = 0.f, o3 = 0.f;
#pragma unroll 10
        for (int c = 0; c < N_CAMP; ++c) {
            const float a = __builtin_nontemporal_load(arow + (size_t)c * ROW);
            o1 = fmaf(a, sb0[c], o1);
            o2 = fmaf(a, sb1[c], o2);
            o3 = fmaf(a, sb2[c], o3);
        }

        const float e1 = __expf(smu[0] + o1);
        const float e2 = __expf(smu[1] + o2);
        const float e3 = __expf(smu[2] + o3);
        const float inv0 = __frcp_rn(1.0f + e1);
        const float inv1 = __frcp_rn(1.0f + e2 + e3);

        float* qo = out + ((size_t)b * DAYS + d) * 9;
        __builtin_nontemporal_store(fmaxf(inv0,      BASIS), &qo[0]);
        __builtin_nontemporal_store(fmaxf(e1 * inv0, BASIS), &qo[1]);
        __builtin_nontemporal_store(BASIS,                   &qo[2]);
        __builtin_nontemporal_store(fmaxf(e2 * inv1, BASIS), &qo[3]);
        __builtin_nontemporal_store(fmaxf(inv1,      BASIS), &qo[4]);
        __builtin_nontemporal_store(fmaxf(e3 * inv1, BASIS), &qo[5]);
        __builtin_nontemporal_store(BASIS,                   &qo[6]);
        __builtin_nontemporal_store(BASIS,                   &qo[7]);
        __builtin_nontemporal_store(1.0f,                    &qo[8]);
    }
}

extern "C" void kernel_launch(void* const* d_in, const int* in_sizes, int n_in,
                              void* d_out, int out_size, void* d_ws, size_t ws_size,
                              hipStream_t stream)
{
    const float* adstock    = (const float*)d_in[0];
    const float* mu         = (const float*)d_in[1];
    const float* beta       = (const float*)d_in[2];
    const float* init_prob  = (const float*)d_in[3];
    const float* click_prob = (const float*)d_in[4];
    float* out = (float*)d_out;

    transition_prob_kernel<<<dim3(BATCH), dim3(NTHR), 0, stream>>>(
        adstock, mu, beta, init_prob, click_prob, out);
}

// Round 8
// 67.118 us; speedup vs baseline: 1.2047x; 1.2047x over previous
//
#include <hip/hip_runtime.h>

#define N_CAMP 50
#define DAYS   365
#define ROW    366          // DAYS+1
#define BASIS  1e-10f
#define BATCH  4096
#define NTHR   384

// R6 winning structure: one block per batch element, thread d computes day d
// via 50 scalar dword loads (wave reads 256 B contiguous per campaign),
// single dispatch, __expf/__frcp_rn, nontemporal stores (NT loads reverted --
// R7 showed they defeat intra-block line reuse).
// R8 change: unroll 10 -> 25 for deeper per-thread memory-level parallelism.
__global__ __launch_bounds__(NTHR)
void transition_prob_kernel(const float* __restrict__ adstock,
                            const float* __restrict__ mu,
                            const float* __restrict__ beta,
                            const float* __restrict__ init_prob,
                            const float* __restrict__ click_prob,
                            float* __restrict__ out)
{
    __shared__ float sb0[N_CAMP];
    __shared__ float sb1[N_CAMP];
    __shared__ float sb2[N_CAMP];
    __shared__ float smu[3];

    const int tid = threadIdx.x;
    const int b   = blockIdx.x;

    if (tid < 3 * N_CAMP) {
        const int c = tid / 3;
        const int k = tid % 3;
        const float v = beta[tid];
        if (k == 0) sb0[c] = v;
        else if (k == 1) sb1[c] = v;
        else sb2[c] = v;
    }
    if (tid < 3) smu[tid] = mu[tid];
    __syncthreads();

    // Fold the two scalar sigmoids in (thread 383 never computes a day).
    if (b == 0 && tid == NTHR - 1) {
        const size_t base = (size_t)BATCH * DAYS * 9;
        __builtin_nontemporal_store(1.0f / (1.0f + __expf(-init_prob[0])), &out[base + 0]);
        __builtin_nontemporal_store(1.0f / (1.0f + __expf(-click_prob[0])), &out[base + 1]);
    }

    const int d = tid;
    if (d < DAYS) {
        const float* arow = adstock + (size_t)b * (N_CAMP * ROW) + (d + 1);

        float o1 = 0.f, o2 = 0.f, o3 = 0.f;
#pragma unroll 25
        for (int c = 0; c < N_CAMP; ++c) {
            const float a = arow[(size_t)c * ROW];
            o1 = fmaf(a, sb0[c], o1);
            o2 = fmaf(a, sb1[c], o2);
            o3 = fmaf(a, sb2[c], o3);
        }

        const float e1 = __expf(smu[0] + o1);
        const float e2 = __expf(smu[1] + o2);
        const float e3 = __expf(smu[2] + o3);
        const float inv0 = __frcp_rn(1.0f + e1);
        const float inv1 = __frcp_rn(1.0f + e2 + e3);

        float* qo = out + ((size_t)b * DAYS + d) * 9;
        __builtin_nontemporal_store(fmaxf(inv0,      BASIS), &qo[0]);
        __builtin_nontemporal_store(fmaxf(e1 * inv0, BASIS), &qo[1]);
        __builtin_nontemporal_store(BASIS,                   &qo[2]);
        __builtin_nontemporal_store(fmaxf(e2 * inv1, BASIS), &qo[3]);
        __builtin_nontemporal_store(fmaxf(inv1,      BASIS), &qo[4]);
        __builtin_nontemporal_store(fmaxf(e3 * inv1, BASIS), &qo[5]);
        __builtin_nontemporal_store(BASIS,                   &qo[6]);
        __builtin_nontemporal_store(BASIS,                   &qo[7]);
        __builtin_nontemporal_store(1.0f,                    &qo[8]);
    }
}

extern "C" void kernel_launch(void* const* d_in, const int* in_sizes, int n_in,
                              void* d_out, int out_size, void* d_ws, size_t ws_size,
                              hipStream_t stream)
{
    const float* adstock    = (const float*)d_in[0];
    const float* mu         = (const float*)d_in[1];
    const float* beta       = (const float*)d_in[2];
    const float* init_prob  = (const float*)d_in[3];
    const float* click_prob = (const float*)d_in[4];
    float* out = (float*)d_out;

    transition_prob_kernel<<<dim3(BATCH), dim3(NTHR), 0, stream>>>(
        adstock, mu, beta, init_prob, click_prob, out);
}